// Round 2
// baseline (460.266 us; speedup 1.0000x reference)
//
#include <hip/hip_runtime.h>
#include <hip/hip_bf16.h>
#include <cstdint>
#include <cstddef>

#define BQ    4
#define NTOK  8192
#define CDIM  512
#define MDIM  128
#define NA    4096
#define RSEL  2048
#define NKEEP (NTOK - RSEL)   // 6144

// ---------------------------------------------------------------------------
// K1: metric = x @ W^T + b, row-normalize, split even/odd rows into ma/mb.
// grid 256 blocks x 256 thr; tile 128 tokens x 128 outs; K=512 in 4 chunks.
// ---------------------------------------------------------------------------
__global__ __launch_bounds__(256) void k_metric(const float* __restrict__ X,
                                                const float* __restrict__ W,
                                                const float* __restrict__ bias,
                                                float* __restrict__ ma,
                                                float* __restrict__ mb) {
  __shared__ float ldsA[128 * 128];
  __shared__ float ldsB[128 * 128];
  __shared__ float snorm[128 * 16];
  __shared__ float sinv[128];
  const int t = threadIdx.x;
  const int tok0 = blockIdx.x * 128;
  const int r16 = t & 15, g = t >> 4;

  float acc[8][8];
#pragma unroll
  for (int i = 0; i < 8; ++i)
#pragma unroll
    for (int j = 0; j < 8; ++j) acc[i][j] = 0.f;

  for (int kc = 0; kc < 4; ++kc) {
    __syncthreads();
#pragma unroll
    for (int it = 0; it < 16; ++it) {
      int f = it * 256 + t;
      int row = f >> 5, k4 = f & 31;
      float4 xv = *(const float4*)(X + (size_t)(tok0 + row) * CDIM + kc * 128 + k4 * 4);
      *(float4*)&ldsA[row * 128 + ((k4 ^ (row & 7)) << 2)] = xv;
      float4 wv = *(const float4*)(W + (size_t)row * CDIM + kc * 128 + k4 * 4);
      *(float4*)&ldsB[row * 128 + ((k4 ^ ((row >> 3) & 7)) << 2)] = wv;
    }
    __syncthreads();
#pragma unroll 4
    for (int kq = 0; kq < 32; ++kq) {
      float4 av[8], bv[8];
#pragma unroll
      for (int i = 0; i < 8; ++i) {
        int r = r16 + (i << 4);
        av[i] = *(const float4*)&ldsA[r * 128 + ((kq ^ (r & 7)) << 2)];
      }
#pragma unroll
      for (int j = 0; j < 8; ++j) {
        int c = (g << 3) + j;
        bv[j] = *(const float4*)&ldsB[c * 128 + ((kq ^ ((c >> 3) & 7)) << 2)];
      }
#pragma unroll
      for (int i = 0; i < 8; ++i)
#pragma unroll
        for (int j = 0; j < 8; ++j) {
          acc[i][j] = fmaf(av[i].x, bv[j].x, acc[i][j]);
          acc[i][j] = fmaf(av[i].y, bv[j].y, acc[i][j]);
          acc[i][j] = fmaf(av[i].z, bv[j].z, acc[i][j]);
          acc[i][j] = fmaf(av[i].w, bv[j].w, acc[i][j]);
        }
    }
  }

  // epilogue: bias, row L2-norm (reduce across the 16 col-groups), write split
  float bb[8];
#pragma unroll
  for (int j = 0; j < 8; ++j) bb[j] = bias[(g << 3) + j];
#pragma unroll
  for (int i = 0; i < 8; ++i) {
    float s = 0.f;
#pragma unroll
    for (int j = 0; j < 8; ++j) {
      acc[i][j] += bb[j];
      s = fmaf(acc[i][j], acc[i][j], s);
    }
    snorm[(r16 + (i << 4)) * 16 + g] = s;
  }
  __syncthreads();
  if (t < 128) {
    float s = 0.f;
    for (int q = 0; q < 16; ++q) s += snorm[t * 16 + q];
    sinv[t] = 1.0f / sqrtf(s);
  }
  __syncthreads();
#pragma unroll
  for (int i = 0; i < 8; ++i) {
    int r = r16 + (i << 4);
    int tokg = tok0 + r;
    float inv = sinv[r];
    int bq = tokg >> 13, pos = tokg & (NTOK - 1);
    float* dst = ((pos & 1) ? mb : ma) + ((size_t)bq * NA + (pos >> 1)) * MDIM + (g << 3);
    float4 o0, o1;
    o0.x = acc[i][0] * inv; o0.y = acc[i][1] * inv;
    o0.z = acc[i][2] * inv; o0.w = acc[i][3] * inv;
    o1.x = acc[i][4] * inv; o1.y = acc[i][5] * inv;
    o1.z = acc[i][6] * inv; o1.w = acc[i][7] * inv;
    *(float4*)dst = o0;
    *(float4*)(dst + 4) = o1;
  }
}

// ---------------------------------------------------------------------------
// K3: scores = ma @ mb^T, fused max/argmax over c. Each block: 128 a-rows x
// one c-half (2048) in 16 chunks of 128. grid = 4 batch x 32 a-tiles x 2 halves.
// ---------------------------------------------------------------------------
__global__ __launch_bounds__(256) void k_scores(const float* __restrict__ ma,
                                                const float* __restrict__ mb,
                                                float* __restrict__ val_part,
                                                int* __restrict__ idx_part) {
  __shared__ float ldsA[128 * 128];
  __shared__ float ldsB[128 * 128];
  __shared__ float sval[128 * 16];
  __shared__ int   sidx[128 * 16];
  const int t = threadIdx.x;
  const int bi = blockIdx.x;
  const int bq = bi >> 6, rem = bi & 63, half = rem >> 5, at = rem & 31;
  const int r16 = t & 15, g = t >> 4;

  const float* A = ma + ((size_t)bq * NA + at * 128) * MDIM;
#pragma unroll
  for (int it = 0; it < 16; ++it) {
    int f = it * 256 + t;
    int row = f >> 5, k4 = f & 31;
    *(float4*)&ldsA[row * 128 + ((k4 ^ (row & 7)) << 2)] =
        *(const float4*)(A + (size_t)row * MDIM + k4 * 4);
  }

  float bestv[8];
  int besti[8];
#pragma unroll
  for (int i = 0; i < 8; ++i) { bestv[i] = -1e30f; besti[i] = 0x7FFFFFFF; }

  for (int ch = 0; ch < 16; ++ch) {
    const int c0 = half * 2048 + ch * 128;
    const float* Bp = mb + ((size_t)bq * NA + c0) * MDIM;
    __syncthreads();
#pragma unroll
    for (int it = 0; it < 16; ++it) {
      int f = it * 256 + t;
      int row = f >> 5, k4 = f & 31;
      *(float4*)&ldsB[row * 128 + ((k4 ^ ((row >> 3) & 7)) << 2)] =
          *(const float4*)(Bp + (size_t)row * MDIM + k4 * 4);
    }
    __syncthreads();

    float acc[8][8];
#pragma unroll
    for (int i = 0; i < 8; ++i)
#pragma unroll
      for (int j = 0; j < 8; ++j) acc[i][j] = 0.f;

#pragma unroll 4
    for (int kq = 0; kq < 32; ++kq) {
      float4 av[8], bv[8];
#pragma unroll
      for (int i = 0; i < 8; ++i) {
        int r = r16 + (i << 4);
        av[i] = *(const float4*)&ldsA[r * 128 + ((kq ^ (r & 7)) << 2)];
      }
#pragma unroll
      for (int j = 0; j < 8; ++j) {
        int c = (g << 3) + j;
        bv[j] = *(const float4*)&ldsB[c * 128 + ((kq ^ ((c >> 3) & 7)) << 2)];
      }
#pragma unroll
      for (int i = 0; i < 8; ++i)
#pragma unroll
        for (int j = 0; j < 8; ++j) {
          acc[i][j] = fmaf(av[i].x, bv[j].x, acc[i][j]);
          acc[i][j] = fmaf(av[i].y, bv[j].y, acc[i][j]);
          acc[i][j] = fmaf(av[i].z, bv[j].z, acc[i][j]);
          acc[i][j] = fmaf(av[i].w, bv[j].w, acc[i][j]);
        }
    }

    // running max/argmax; c ascending (chunks asc, j asc), strict > keeps lowest c
    const int cbase = c0 + (g << 3);
#pragma unroll
    for (int i = 0; i < 8; ++i)
#pragma unroll
      for (int j = 0; j < 8; ++j) {
        if (acc[i][j] > bestv[i]) { bestv[i] = acc[i][j]; besti[i] = cbase + j; }
      }
  }

  // block reduce across the 16 col-group threads holding each row
#pragma unroll
  for (int i = 0; i < 8; ++i) {
    int r = r16 + (i << 4);
    sval[r * 16 + g] = bestv[i];
    sidx[r * 16 + g] = besti[i];
  }
  __syncthreads();
  if (t < 128) {
    float bv = -1e30f;
    int bx = 0x7FFFFFFF;
    for (int q = 0; q < 16; ++q) {
      float v = sval[t * 16 + q];
      int ii = sidx[t * 16 + q];
      if (v > bv || (v == bv && ii < bx)) { bv = v; bx = ii; }
    }
    size_t o = ((size_t)bq * 2 + half) * NA + at * 128 + t;
    val_part[o] = bv;
    idx_part[o] = bx;
  }
}

// K4: merge the two c-halves (tie -> half 0 = lower c, matching first-argmax)
__global__ void k_merge(const float* __restrict__ val_part,
                        const int* __restrict__ idx_part,
                        float* __restrict__ values, int* __restrict__ node) {
  int i = blockIdx.x * 256 + threadIdx.x;
  if (i >= BQ * NA) return;
  int bq = i >> 12, k = i & (NA - 1);
  size_t o0 = ((size_t)bq * 2 + 0) * NA + k;
  size_t o1 = ((size_t)bq * 2 + 1) * NA + k;
  float v0 = val_part[o0], v1 = val_part[o1];
  bool take1 = (v1 > v0);
  values[i] = take1 ? v1 : v0;
  node[i]   = take1 ? idx_part[o1] : idx_part[o0];
}

// K5: exact top-2048 of 4096 per batch. Bitonic sort of (desc val, asc idx)
// keys in LDS -- replicates jax.lax.top_k ordering/tie-break exactly.
__global__ __launch_bounds__(1024) void k_topk(const float* __restrict__ values,
                                               int* __restrict__ sel) {
  __shared__ unsigned long long keys[NA];
  const int b = blockIdx.x, t = threadIdx.x;
  for (int p = t; p < NA; p += 1024) {
    float v = values[(size_t)b * NA + p];
    unsigned u = __float_as_uint(v);
    unsigned mono = u ^ ((u >> 31) ? 0xFFFFFFFFu : 0x80000000u);
    keys[p] = ((unsigned long long)(~mono) << 32) | (unsigned)p;
  }
  __syncthreads();
  for (int k = 2; k <= NA; k <<= 1) {
    for (int j = k >> 1; j > 0; j >>= 1) {
      for (int p = t; p < NA; p += 1024) {
        int q = p ^ j;
        if (q > p) {
          bool up = ((p & k) == 0);
          unsigned long long a = keys[p], c = keys[q];
          if ((a > c) == up) { keys[p] = c; keys[q] = a; }
        }
      }
      __syncthreads();
    }
  }
  for (int p = t; p < NA; p += 1024) {
    int idx = (int)(keys[p] & 0xFFFFFFFFull);
    sel[(size_t)b * NA + idx] = (p < RSEL) ? 1 : 0;
  }
}

// K6: per-destination merge lists (count + atomicExch linked list)
__global__ void k_build(const int* __restrict__ sel, const int* __restrict__ node,
                        int* __restrict__ cnt, int* __restrict__ head,
                        int* __restrict__ nxt) {
  int i = blockIdx.x * 256 + threadIdx.x;
  if (i >= BQ * NA) return;
  int bq = i >> 12, k = i & (NA - 1);
  if (sel[i]) {
    int dst = node[i];
    atomicAdd(&cnt[(size_t)bq * NA + dst], 1);
    nxt[i] = atomicExch(&head[(size_t)bq * NA + dst], k);
  }
}

// K7: mask scan -> new_idx; ownership output (float32). One block per batch.
__global__ __launch_bounds__(1024) void k_scan(const int* __restrict__ sel,
                                               const int* __restrict__ node,
                                               int* __restrict__ newidx,
                                               float* __restrict__ own) {
  __shared__ int ni[NTOK];
  __shared__ int tot[1024];
  const int b = blockIdx.x, t = threadIdx.x;
  const int base = t * 8;
  int kept[8], run = 0;
#pragma unroll
  for (int e = 0; e < 8; ++e) {
    int idx = base + e;
    int kp = ((idx & 1) == 0) ? 1 : (sel[(size_t)b * NA + (idx >> 1)] ? 0 : 1);
    kept[e] = kp;
    run += kp;
  }
  tot[t] = run;
  __syncthreads();
  for (int off = 1; off < 1024; off <<= 1) {
    int v = (t >= off) ? tot[t - off] : 0;
    __syncthreads();
    tot[t] += v;
    __syncthreads();
  }
  int cum = tot[t] - run;
#pragma unroll
  for (int e = 0; e < 8; ++e) {
    cum += kept[e];
    ni[base + e] = cum - 1;
  }
  __syncthreads();
#pragma unroll
  for (int e = 0; e < 8; ++e) {
    int idx = base + e;
    int ow = kept[e] ? ni[idx] : ni[2 * node[(size_t)b * NA + (idx >> 1)]];
    newidx[(size_t)b * NTOK + idx] = ni[idx];
    own[(size_t)b * NTOK + idx] = (float)ow;
  }
}

// K8: assemble x_final f32 (gather merges via linked list, divide, compact)
__global__ __launch_bounds__(128) void k_assemble(const float* __restrict__ X,
                                                  const int* __restrict__ sel,
                                                  const int* __restrict__ newidx,
                                                  const int* __restrict__ cnt,
                                                  const int* __restrict__ head,
                                                  const int* __restrict__ nxt,
                                                  float* __restrict__ out) {
  const int token = blockIdx.x;            // 0 .. B*NTOK-1
  const int bq = token >> 13, tp = token & (NTOK - 1);
  if ((tp & 1) && sel[(size_t)bq * NA + (tp >> 1)]) return;  // removed row
  const int t = threadIdx.x;
  float4 v = *(const float4*)(X + (size_t)token * CDIM + t * 4);
  if (!(tp & 1)) {
    size_t slot = (size_t)bq * NA + (tp >> 1);
    int c = cnt[slot];
    if (c > 0) {
      int kk = head[slot];
      while (kk >= 0) {
        float4 s = *(const float4*)(X + ((size_t)bq * NTOK + 2 * kk + 1) * CDIM + t * 4);
        v.x += s.x; v.y += s.y; v.z += s.z; v.w += s.w;
        kk = nxt[(size_t)bq * NA + kk];
      }
      float inv = 1.0f / (float)(1 + c);
      v.x *= inv; v.y *= inv; v.z *= inv; v.w *= inv;
    }
  }
  int dst = newidx[(size_t)bq * NTOK + tp];
  *(float4*)(out + ((size_t)bq * NKEEP + dst) * CDIM + t * 4) = v;
}

// ---------------------------------------------------------------------------
extern "C" void kernel_launch(void* const* d_in, const int* in_sizes, int n_in,
                              void* d_out, int out_size, void* d_ws, size_t ws_size,
                              hipStream_t stream) {
  const float* X    = (const float*)d_in[0];
  const float* W    = (const float*)d_in[1];
  const float* bias = (const float*)d_in[2];
  float* out = (float*)d_out;              // f32: x_final (4,6144,512) ++ ownership (4,8192)
  char* ws = (char*)d_ws;

  size_t o = 0;
  float* ma       = (float*)(ws + o); o += (size_t)BQ * NA * MDIM * 4;   // 8 MB
  float* mb       = (float*)(ws + o); o += (size_t)BQ * NA * MDIM * 4;   // 8 MB
  float* val_part = (float*)(ws + o); o += (size_t)BQ * 2 * NA * 4;
  int*   idx_part = (int*)(ws + o);   o += (size_t)BQ * 2 * NA * 4;
  float* values   = (float*)(ws + o); o += (size_t)BQ * NA * 4;
  int*   node     = (int*)(ws + o);   o += (size_t)BQ * NA * 4;
  int*   sel      = (int*)(ws + o);   o += (size_t)BQ * NA * 4;
  int*   cnt      = (int*)(ws + o);   o += (size_t)BQ * NA * 4;
  int*   head     = (int*)(ws + o);   o += (size_t)BQ * NA * 4;
  int*   nxt      = (int*)(ws + o);   o += (size_t)BQ * NA * 4;
  int*   newidx   = (int*)(ws + o);   o += (size_t)BQ * NTOK * 4;
  (void)in_sizes; (void)n_in; (void)out_size; (void)ws_size;

  hipMemsetAsync(cnt, 0, (size_t)BQ * NA * 4, stream);
  hipMemsetAsync(head, 0xFF, (size_t)BQ * NA * 4, stream);

  k_metric<<<256, 256, 0, stream>>>(X, W, bias, ma, mb);
  k_scores<<<256, 256, 0, stream>>>(ma, mb, val_part, idx_part);
  k_merge<<<(BQ * NA + 255) / 256, 256, 0, stream>>>(val_part, idx_part, values, node);
  k_topk<<<BQ, 1024, 0, stream>>>(values, sel);
  k_build<<<(BQ * NA + 255) / 256, 256, 0, stream>>>(sel, node, cnt, head, nxt);
  k_scan<<<BQ, 1024, 0, stream>>>(sel, node, newidx,
                                  out + (size_t)BQ * NKEEP * CDIM);
  k_assemble<<<BQ * NTOK, 128, 0, stream>>>(X, sel, newidx, cnt, head, nxt, out);
}